// Round 7
// baseline (269.845 us; speedup 1.0000x reference)
//
#include <hip/hip_runtime.h>
#include <hip/hip_bf16.h>
#include <math.h>

typedef __attribute__((ext_vector_type(8))) short short8;
typedef __attribute__((ext_vector_type(4))) short short4v;
typedef __attribute__((ext_vector_type(4))) float f32x4;
typedef __attribute__((ext_vector_type(2))) unsigned int uint2v;
typedef unsigned int u32;

// v_mfma_f32_16x16x16_bf16 (gfx90a-lineage "_1k" builtin name; valid on gfx950)
#define MFMA16(a, b, c) __builtin_amdgcn_mfma_f32_16x16x16bf16_1k(a, b, c, 0, 0, 0)
#define MFMA32(a, b, c) __builtin_amdgcn_mfma_f32_16x16x32_bf16(a, b, c, 0, 0, 0)

#define GLB(p) ((const __attribute__((address_space(1))) u32*)(p))
#define LDS(p) ((__attribute__((address_space(3))) u32*)(p))

// softmax scale folded into Q: 1/sqrt(64) * log2(e)
#define QSCALE 0.18033688011111204f

// K/V chunk tile geometry (padded in GLOBAL so global_load_lds DMA preserves padding)
#define KV_STRIDE 72            // halves per row (64 data + 8 pad) -> 2-way-free LDS banks
#define KV_TILE 4608            // halves per 64-row tile (64*72)
#define KV_CHUNK 9216           // halves per chunk (K tile + V^T tile)

__device__ __forceinline__ unsigned short f2bf(float f) {
  unsigned int u = __float_as_uint(f);
  u += 0x7fffu + ((u >> 16) & 1u);
  return (unsigned short)(u >> 16);
}

// ---------------- prep kernels ----------------

__global__ __launch_bounds__(256) void cvt_bf16(const float* __restrict__ in,
                                                unsigned short* __restrict__ out, int n4) {
  int i = blockIdx.x * blockDim.x + threadIdx.x;
  if (i < n4) {
    float4 f = ((const float4*)in)[i];
    ushort4 o;
    o.x = f2bf(f.x); o.y = f2bf(f.y); o.z = f2bf(f.z); o.w = f2bf(f.w);
    ((ushort4*)out)[i] = o;
  }
}

// in: f32 [R][C] row-major -> out: bf16 [C][R] row-major
__global__ __launch_bounds__(256) void transpose_cvt(const float* __restrict__ in,
                                                     unsigned short* __restrict__ out,
                                                     int R, int C) {
  __shared__ float tile[32][33];
  int bx = blockIdx.x * 32;
  int by = blockIdx.y * 32;
  int tx = threadIdx.x, ty = threadIdx.y;  // block (32,8)
#pragma unroll
  for (int i = 0; i < 32; i += 8)
    tile[ty + i][tx] = in[(size_t)(by + ty + i) * C + bx + tx];
  __syncthreads();
#pragma unroll
  for (int i = 0; i < 32; i += 8)
    out[(size_t)(bx + ty + i) * R + by + tx] = f2bf(tile[tx][ty + i]);
}

// ---------------- GEMM: C[M][N] = A[M][K] * Bt[N][K]^T + bias ----------------
// ROUND-6 VERIFIED (262.7us total): 128x128 tile, 4 waves, BK=32, packed-pair
// XOR swizzle (0 bank conflicts), double-buffered LDS with early-issue staging
// (T3 minimum 2-phase):
//   prologue: STAGE(buf0, tile0); __syncthreads();
//   iter t:   STAGE(buf^1, tile t+1);     // overlaps with this tile's compute
//             ds_read buf[cur]; 16 MFMA;
//             __syncthreads();            // drains stage(t+1) + WAR protection
// Swizzle: tile = 64 pair-rows (128B) x 8 slots (16B); logical (row r, k):
// s_log=(r&1)*4+(k>>3) stored at s_log^((r>>1)&7); DMA dest LINEAR, inverse
// permutation on the global source; read slot ((l15&1)*4+quad)^(l15>>1).
// MODE 0: q_ws [B][H][T][D] bf16 (scaled by QSCALE) and K tiles via MFMA-identity
//         transpose + packed ushort4 stores; V^T tiles packed directly.
// MODE 1: write f32 to outf [M][N].

template <int MODE>
__global__ __launch_bounds__(256)
void gemm_bt(const unsigned short* __restrict__ A, const unsigned short* __restrict__ Bt,
             const float* __restrict__ bias, float* __restrict__ outf,
             unsigned short* __restrict__ q_ws, unsigned short* __restrict__ kv_ws,
             int M, int N, int K) {
  __shared__ unsigned short As[2][128 * 32];
  __shared__ unsigned short Bs[2][128 * 32];
  const int tid = threadIdx.x;
  const int wid = tid >> 6;
  const int lane = tid & 63;
  const int quad = lane >> 4;
  const int l15 = lane & 15;
  const int m0 = blockIdx.x * 128;
  const int n0 = blockIdx.y * 128;
  const int wm = (wid >> 1) * 64;
  const int wn = (wid & 1) * 64;

  // global_load_lds staging: lane i of wave w -> LDS byte (w*32 rows)*64 + i*16 (LINEAR)
  const int srow = wid * 32 + (lane >> 2);
  const int scol = (lane & 3) * 8;
  // inverse swizzle on the global source: this thread's linear LDS slot is
  // s_phys = ((srow&1)*4 + (lane&3)) in pair P=srow>>1 (P&7 == lane>>3);
  // it must receive logical slot s_log = s_phys ^ (P&7).
  const int sphys = ((lane >> 2) & 1) * 4 + (lane & 3);
  const int slog = sphys ^ (lane >> 3);
  const int r_log = (srow & ~1) | (slog >> 2);
  const int koff = (slog & 3) * 8;
  const unsigned short* ga0 = A + (size_t)(m0 + r_log) * K + koff;
  const unsigned short* ga1 = ga0 + (size_t)16 * K;   // srow+16: P&7 unchanged -> same slog
  const unsigned short* gb0 = Bt + (size_t)(n0 + r_log) * K + koff;
  const unsigned short* gb1 = gb0 + (size_t)16 * K;
  const int la0 = srow * 32 + scol;
  const int la1 = la0 + 16 * 32;

  // fragment-read addressing: row r = w? + i*16 + l15, slot ((r&1)*4+quad)^((r>>1)&7)
  // -> addr = (r>>1)*64 + slot*8 ; (r>>1)&7 == l15>>1 (wm, i*16 are 16-aligned)
  const int sA = (((l15 & 1) * 4 + quad) ^ (l15 >> 1)) * 8;
  const int aBase = wm * 32 + (l15 >> 1) * 64 + sA;  // + i*512
  const int bBase = wn * 32 + (l15 >> 1) * 64 + sA;  // + j*512

#define STAGE(buf, k0)                                                                   \
  do {                                                                                   \
    __builtin_amdgcn_global_load_lds(GLB(ga0 + (k0)), LDS(&As[buf][la0]), 16, 0, 0);     \
    __builtin_amdgcn_global_load_lds(GLB(ga1 + (k0)), LDS(&As[buf][la1]), 16, 0, 0);     \
    __builtin_amdgcn_global_load_lds(GLB(gb0 + (k0)), LDS(&Bs[buf][la0]), 16, 0, 0);     \
    __builtin_amdgcn_global_load_lds(GLB(gb1 + (k0)), LDS(&Bs[buf][la1]), 16, 0, 0);     \
  } while (0)

  f32x4 acc[4][4];
#pragma unroll
  for (int i = 0; i < 4; i++)
#pragma unroll
    for (int j = 0; j < 4; j++) acc[i][j] = (f32x4){0.f, 0.f, 0.f, 0.f};

  STAGE(0, 0);
  __syncthreads();  // drain prologue stage

  int cur = 0;
  for (int k0 = 0; k0 < K; k0 += 32, cur ^= 1) {
    if (k0 + 32 < K) STAGE(cur ^ 1, k0 + 32);  // overlaps with this tile's compute
    short8 af[4], bf[4];
#pragma unroll
    for (int i = 0; i < 4; i++)
      af[i] = *(const short8*)(&As[cur][aBase + i * 512]);
#pragma unroll
    for (int j = 0; j < 4; j++)
      bf[j] = *(const short8*)(&Bs[cur][bBase + j * 512]);
#pragma unroll
    for (int i = 0; i < 4; i++)
#pragma unroll
      for (int j = 0; j < 4; j++)
        acc[i][j] = MFMA32(af[i], bf[j], acc[i][j]);
    __syncthreads();  // drains stage(t+1) + all reads of buf[cur] complete
  }
#undef STAGE

  const int colbase = n0 + wn;  // wave-uniform, 64-aligned; never straddles a 1024-boundary
  const int which = colbase >> 10;

  if (MODE == 0) {
    const int h = (colbase & 1023) >> 6;  // wave-uniform head
    if (which == 2) {
      // ---- V path: acc already d-per-lane / t-consecutive-per-reg; pack ushort4 ----
#pragma unroll
      for (int j = 0; j < 4; j++) {
        const float bv = bias[colbase + j * 16 + l15];
        const int d = j * 16 + l15;
#pragma unroll
        for (int i = 0; i < 4; i++) {
          const int t = m0 + wm + i * 16 + quad * 4;
          const int b = t >> 11;
          const int tt = t & 2047;
          ushort4 pv;
          pv.x = f2bf(acc[i][j][0] + bv);
          pv.y = f2bf(acc[i][j][1] + bv);
          pv.z = f2bf(acc[i][j][2] + bv);
          pv.w = f2bf(acc[i][j][3] + bv);
          const size_t cbase = ((size_t)((b * 16 + h) * 32) + (tt >> 6)) * KV_CHUNK + KV_TILE;
          *(ushort4*)(&kv_ws[cbase + (size_t)d * KV_STRIDE + (tt & 63)]) = pv;
        }
      }
    } else {
      // ---- Q/K path: MFMA-identity transpose -> per-lane 4 consecutive d -> ushort4 ----
      short4v idf;
#pragma unroll
      for (int j4 = 0; j4 < 4; j4++)
        idf[j4] = (quad * 4 + j4 == l15) ? (short)0x3F80 : (short)0;
#pragma unroll
      for (int j = 0; j < 4; j++) {
        const float bv = bias[colbase + j * 16 + l15];
#pragma unroll
        for (int i = 0; i < 4; i++) {
          short4v pf;
          if (which == 0) {
#pragma unroll
            for (int r = 0; r < 4; r++) pf[r] = (short)f2bf((acc[i][j][r] + bv) * QSCALE);
          } else {
#pragma unroll
            for (int r = 0; r < 4; r++) pf[r] = (short)f2bf(acc[i][j][r] + bv);
          }
          f32x4 dt = MFMA16(pf, idf, ((f32x4){0.f, 0.f, 0.f, 0.f}));
          const int t = m0 + wm + i * 16 + l15;  // lane -> t
          const int b = t >> 11;
          const int tt = t & 2047;
          const int dd = j * 16 + quad * 4;  // 4 consecutive d in regs
          ushort4 qv;
          qv.x = f2bf(dt[0]);
          qv.y = f2bf(dt[1]);
          qv.z = f2bf(dt[2]);
          qv.w = f2bf(dt[3]);
          if (which == 0) {
            *(ushort4*)(&q_ws[(((size_t)((b * 16 + h) * 2048) + tt) * 64) + dd]) = qv;
          } else {
            const size_t cbase = ((size_t)((b * 16 + h) * 32) + (tt >> 6)) * KV_CHUNK;
            *(ushort4*)(&kv_ws[cbase + (size_t)(tt & 63) * KV_STRIDE + dd]) = qv;
          }
        }
      }
    }
  } else {
#pragma unroll
    for (int j = 0; j < 4; j++) {
      const int col = colbase + j * 16 + l15;
      const float bv = bias[col];
#pragma unroll
      for (int i = 0; i < 4; i++) {
#pragma unroll
        for (int r = 0; r < 4; r++) {
          const int row = m0 + wm + i * 16 + quad * 4 + r;
          outf[(size_t)row * N + col] = acc[i][j][r] + bv;
        }
      }
    }
  }
}

// ---------------- flash attention (transposed-S, 2-way paired, DMA-pipelined) ----------
// q_ws: bf16 [B][H][T][D] (pre-scaled by 0.125*log2e); kv_ws: padded chunk tiles.
// y_ws: bf16 [B][T][C].
//
// ROUND 7: controlled re-test of the round-5 F=2 occupancy split with ONE
// variable removed: NO __launch_bounds__ min-waves clamp. r5's failure is
// attributed to the (256,4) clamp (VGPR cap 128 < ~130 natural -> spill/remat
// around DMA+barrier code); the F=2 algebra itself is r3-identical and was
// re-derived 3x: pairing {ip,31-ip} is a complete disjoint cover, nch=32-ip
// covers the larger tile, break/skip/mask conditions and the quad lsum
// reduction are unchanged, epilogue writes each row once.
// Grid (16,64) = 1024 blocks, block ip owns pair {ip, 31-ip} (33 units each,
// balanced). F=2 halves o/qfr state (~110-125 VGPR natural): if the compiler
// lands <=128 VGPR -> 4 waves/SIMD (m69 steps) -> 4 blocks/CU (LDS 144KB),
// 2x TLP on a latency-bound kernel; if >128 -> neutral but correct, and the
// clamp is convicted as r5's culprit.
// One barrier per 64-key chunk; DMA for c+1 issued right after barrier c.
// Static max: p = exp2(s) directly (softmax scale-invariant in f32; masked -> 0).

__global__ __launch_bounds__(256)
void attn_fwd(const unsigned short* __restrict__ q_ws, const unsigned short* __restrict__ kv_ws,
              unsigned short* __restrict__ y_ws) {
  __shared__ unsigned short KV[2][KV_CHUNK];  // [K 64x72 | V^T 64x72] per buffer
  const int tid = threadIdx.x;
  const int w = tid >> 6;
  const int lane = tid & 63;
  const int quad = lane >> 4;
  const int l15 = lane & 15;
  const int ip = blockIdx.x;  // 0..15 pair index
  const int bh = blockIdx.y;
  const unsigned short* Qp = q_ws + (size_t)bh * 2048 * 64;
  const unsigned short* KVp = kv_ws + (size_t)bh * 32 * KV_CHUNK;

  int qT[2];
  qT[0] = ip * 64 + w * 16;
  qT[1] = (31 - ip) * 64 + w * 16;

  short8 qfr[2][2];
#pragma unroll
  for (int f = 0; f < 2; f++)
#pragma unroll
    for (int c = 0; c < 2; c++)
      qfr[f][c] = *(const short8*)(Qp + (size_t)(qT[f] + l15) * 64 + c * 32 + quad * 8);

  f32x4 o[2][4];
#pragma unroll
  for (int f = 0; f < 2; f++)
#pragma unroll
    for (int db = 0; db < 4; db++) o[f][db] = (f32x4){0.f, 0.f, 0.f, 0.f};
  float lsum[2] = {0.f, 0.f};  // per-lane partial; reduced in epilogue

  const int nch = 32 - ip;  // 64-key chunks (covers largest tile qT[1])

  // stage chunk 0 into buffer 0 (DMA, no VGPR round trip)
  for (int i = w; i < 18; i += 4)
    __builtin_amdgcn_global_load_lds(GLB(KVp + i * 512 + lane * 8),
                                     LDS(&KV[0][i * 512 + lane * 8]), 16, 0, 0);

  for (int c = 0; c < nch; c++) {
    __syncthreads();  // drains DMA for chunk c (vmcnt0 before barrier)
    const int buf = c & 1;
    if (c + 1 < nch) {  // issue DMA for next chunk; consumed at next barrier
      const unsigned short* src = KVp + (size_t)(c + 1) * KV_CHUNK;
      for (int i = w; i < 18; i += 4)
        __builtin_amdgcn_global_load_lds(GLB(src + i * 512 + lane * 8),
                                         LDS(&KV[buf ^ 1][i * 512 + lane * 8]), 16, 0, 0);
    }
    const unsigned short* Ksb = KV[buf];            // [key][d] stride 72
    const unsigned short* Vtb = KV[buf] + KV_TILE;  // [d][key] stride 72
    const int kbase = c * 64;

#pragma unroll
    for (int tb = 0; tb < 2; tb++) {
      const int kb = kbase + tb * 32;
      if (kb > qT[1] + 15) break;  // wave-uniform
      const int kloc = tb * 32;
      short8 kf[2][2];
#pragma unroll
      for (int t2 = 0; t2 < 2; t2++)
#pragma unroll
        for (int cc = 0; cc < 2; cc++)
          kf[t2][cc] =
              *(const short8*)(&Ksb[(kloc + t2 * 16 + l15) * KV_STRIDE + cc * 32 + quad * 8]);
      short4v vf[2][4];
#pragma unroll
      for (int t2 = 0; t2 < 2; t2++)
#pragma unroll
        for (int db = 0; db < 4; db++)
          vf[t2][db] =
              *(const short4v*)(&Vtb[(db * 16 + l15) * KV_STRIDE + kloc + t2 * 16 + quad * 4]);

#pragma unroll
      for (int f = 0; f < 2; f++) {
        const int qf0 = qT[f];
        if (kb > qf0 + 15) continue;  // wave-uniform skip
        // S^T[key][q]: A=K rows (m=key), B=Q rows (n=q)
        f32x4 s0 = (f32x4){0.f, 0.f, 0.f, 0.f};
        f32x4 s1 = (f32x4){0.f, 0.f, 0.f, 0.f};
        s0 = MFMA32(kf[0][0], qfr[f][0], s0);
        s0 = MFMA32(kf[0][1], qfr[f][1], s0);
        s1 = MFMA32(kf[1][0], qfr[f][0], s1);
        s1 = MFMA32(kf[1][1], qfr[f][1], s1);
        const int qg = qf0 + l15;
        if (kb + 31 > qf0) {  // diagonal-crossing: apply causal mask
#pragma unroll
          for (int r = 0; r < 4; r++) {
            if (kb + quad * 4 + r > qg) s0[r] = -INFINITY;
            if (kb + 16 + quad * 4 + r > qg) s1[r] = -INFINITY;
          }
        }
        float p[8];
#pragma unroll
        for (int r = 0; r < 4; r++) {
          p[r] = __builtin_amdgcn_exp2f(s0[r]);
          p[4 + r] = __builtin_amdgcn_exp2f(s1[r]);
        }
        lsum[f] += ((p[0] + p[1]) + (p[2] + p[3])) + ((p[4] + p[5]) + (p[6] + p[7]));
        // pack P to bf16 B-frags for 16x16x16 (k=quad*4+j matches C-layout rows)
        u32 u[8];
#pragma unroll
        for (int i = 0; i < 8; i++) u[i] = __float_as_uint(p[i]) + 0x8000u;
        uint2v t0, t1;
        t0.x = __builtin_amdgcn_perm(u[1], u[0], 0x07060302u);
        t0.y = __builtin_amdgcn_perm(u[3], u[2], 0x07060302u);
        t1.x = __builtin_amdgcn_perm(u[5], u[4], 0x07060302u);
        t1.y = __builtin_amdgcn_perm(u[7], u[6], 0x07060302u);
        short4v pf0 = __builtin_bit_cast(short4v, t0);
        short4v pf1 = __builtin_bit_cast(short4v, t1);
#pragma unroll
        for (int db = 0; db < 4; db++) {
          o[f][db] = MFMA16(vf[0][db], pf0, o[f][db]);
          o[f][db] = MFMA16(vf[1][db], pf1, o[f][db]);
        }
      }
    }
  }

  const int b = bh >> 4, h = bh & 15;
#pragma unroll
  for (int f = 0; f < 2; f++) {
    float ls = lsum[f];
    ls += __shfl_xor(ls, 16);
    ls += __shfl_xor(ls, 32);
    const int qg = qT[f] + l15;
    const float inv = 1.0f / ls;
    const size_t rowoff = ((size_t)(b * 2048 + qg)) * 1024 + h * 64;
#pragma unroll
    for (int db = 0; db < 4; db++) {
      ushort4 ov;
      ov.x = f2bf(o[f][db][0] * inv);
      ov.y = f2bf(o[f][db][1] * inv);
      ov.z = f2bf(o[f][db][2] * inv);
      ov.w = f2bf(o[f][db][3] * inv);
      *(ushort4*)(y_ws + rowoff + db * 16 + quad * 4) = ov;
    }
  }
}

// ---------------- launch ----------------

extern "C" void kernel_launch(void* const* d_in, const int* in_sizes, int n_in,
                              void* d_out, int out_size, void* d_ws, size_t ws_size,
                              hipStream_t stream) {
  const float* x = (const float*)d_in[0];
  const float* w_attn = (const float*)d_in[1];
  const float* b_attn = (const float*)d_in[2];
  const float* w_proj = (const float*)d_in[3];
  const float* b_proj = (const float*)d_in[4];
  float* out = (float*)d_out;

  // Workspace: ~80 MB total (96.5 MB in an earlier round overflowed ws_size).
  unsigned short* xb = (unsigned short*)d_ws;          // 8192*1024 (bf16 x)
  unsigned short* wat = xb + (size_t)8192 * 1024;      // 3072*1024 (w_attn^T)
  unsigned short* wpt = wat + (size_t)3072 * 1024;     // 1024*1024 (w_proj^T)
  unsigned short* q_ws = wpt + (size_t)1024 * 1024;    // [B][H][T][D]
  unsigned short* kv_ws = q_ws + (size_t)8388608;      // [bh][chunk] padded K|V^T tiles
  // y_ws ALIASES xb: xb is only read by gemm0, which completes before attn writes y.
  unsigned short* y_ws = xb;                           // [B][T][C]

  cvt_bf16<<<8192, 256, 0, stream>>>(x, xb, 2097152);
  transpose_cvt<<<dim3(96, 32), dim3(32, 8), 0, stream>>>(w_attn, wat, 1024, 3072);
  transpose_cvt<<<dim3(32, 32), dim3(32, 8), 0, stream>>>(w_proj, wpt, 1024, 1024);

  gemm_bt<0><<<dim3(64, 24), 256, 0, stream>>>(xb, wat, b_attn, nullptr, q_ws, kv_ws,
                                               8192, 3072, 1024);
  attn_fwd<<<dim3(16, 64), 256, 0, stream>>>(q_ws, kv_ws, y_ws);
  gemm_bt<1><<<dim3(64, 8), 256, 0, stream>>>(y_ws, wpt, b_proj, out, nullptr, nullptr,
                                              8192, 1024, 1024);
}

// Round 8
// 256.522 us; speedup vs baseline: 1.0519x; 1.0519x over previous
//
#include <hip/hip_runtime.h>
#include <hip/hip_bf16.h>
#include <math.h>

typedef __attribute__((ext_vector_type(8))) short short8;
typedef __attribute__((ext_vector_type(4))) short short4v;
typedef __attribute__((ext_vector_type(4))) float f32x4;
typedef __attribute__((ext_vector_type(2))) unsigned int uint2v;
typedef unsigned int u32;

// v_mfma_f32_16x16x16_bf16 (gfx90a-lineage "_1k" builtin name; valid on gfx950)
#define MFMA16(a, b, c) __builtin_amdgcn_mfma_f32_16x16x16bf16_1k(a, b, c, 0, 0, 0)
#define MFMA32(a, b, c) __builtin_amdgcn_mfma_f32_16x16x32_bf16(a, b, c, 0, 0, 0)

#define GLB(p) ((const __attribute__((address_space(1))) u32*)(p))
#define LDS(p) ((__attribute__((address_space(3))) u32*)(p))

// softmax scale folded into Q: 1/sqrt(64) * log2(e)
#define QSCALE 0.18033688011111204f

// K/V chunk tile geometry (padded in GLOBAL so global_load_lds DMA preserves padding)
#define KV_STRIDE 72            // halves per row (64 data + 8 pad) -> 2-way-free LDS banks
#define KV_TILE 4608            // halves per 64-row tile (64*72)
#define KV_CHUNK 9216           // halves per chunk (K tile + V^T tile)

__device__ __forceinline__ unsigned short f2bf(float f) {
  unsigned int u = __float_as_uint(f);
  u += 0x7fffu + ((u >> 16) & 1u);
  return (unsigned short)(u >> 16);
}

// ---------------- fused prep kernel ----------------
// ROUND 8: one launch replaces {cvt_bf16, transpose_cvt(w_attn), transpose_cvt(w_proj)}.
// Block ranges (block-uniform branch -> __syncthreads safe):
//   [0,2048):      x f32 -> xb bf16, 4 float4/thread, 2048*256*4 = 2097152 exactly.
//   [2048,5120):   w_attn [1024][3072] -> wat [3072][1024] (tiles 96x32)
//   [5120,6144):   w_proj [1024][1024] -> wpt [1024][1024] (tiles 32x32)

__global__ __launch_bounds__(256)
void prep_fused(const float* __restrict__ x, unsigned short* __restrict__ xb,
                const float* __restrict__ w_attn, unsigned short* __restrict__ wat,
                const float* __restrict__ w_proj, unsigned short* __restrict__ wpt) {
  __shared__ float tile[32][33];
  const int bid = blockIdx.x;
  const int tid = threadIdx.x;
  if (bid < 2048) {
    int i = bid * 256 + tid;
#pragma unroll
    for (int r = 0; r < 4; r++, i += 2048 * 256) {
      float4 f = ((const float4*)x)[i];
      ushort4 o;
      o.x = f2bf(f.x); o.y = f2bf(f.y); o.z = f2bf(f.z); o.w = f2bf(f.w);
      ((ushort4*)xb)[i] = o;
    }
  } else {
    const float* in;
    unsigned short* out;
    int R, C, bx, by;
    if (bid < 5120) {
      const int lb = bid - 2048;
      in = w_attn; out = wat; R = 1024; C = 3072;
      bx = (lb % 96) * 32; by = (lb / 96) * 32;
    } else {
      const int lb = bid - 5120;
      in = w_proj; out = wpt; R = 1024; C = 1024;
      bx = (lb & 31) * 32; by = (lb >> 5) * 32;
    }
    const int tx = tid & 31, ty = tid >> 5;  // (32,8) mapping
#pragma unroll
    for (int i = 0; i < 32; i += 8)
      tile[ty + i][tx] = in[(size_t)(by + ty + i) * C + bx + tx];
    __syncthreads();
#pragma unroll
    for (int i = 0; i < 32; i += 8)
      out[(size_t)(bx + ty + i) * R + by + tx] = f2bf(tile[tx][ty + i]);
  }
}

// ---------------- GEMM: C[M][N] = A[M][K] * Bt[N][K]^T + bias ----------------
// ROUND-6 VERIFIED (262.7us total): 128x128 tile, 4 waves, BK=32, packed-pair
// XOR swizzle (0 bank conflicts), double-buffered LDS with early-issue staging
// (T3 minimum 2-phase):
//   prologue: STAGE(buf0, tile0); __syncthreads();
//   iter t:   STAGE(buf^1, tile t+1);     // overlaps with this tile's compute
//             ds_read buf[cur]; 16 MFMA;
//             __syncthreads();            // drains stage(t+1) + WAR protection
// Swizzle: tile = 64 pair-rows (128B) x 8 slots (16B); logical (row r, k):
// s_log=(r&1)*4+(k>>3) stored at s_log^((r>>1)&7); DMA dest LINEAR, inverse
// permutation on the global source; read slot ((l15&1)*4+quad)^(l15>>1).
// MODE 0: q_ws [B][H][T][D] bf16 (scaled by QSCALE) and K tiles via MFMA-identity
//         transpose + packed ushort4 stores; V^T tiles packed directly.
// MODE 1: write f32 to outf [M][N].

template <int MODE>
__global__ __launch_bounds__(256)
void gemm_bt(const unsigned short* __restrict__ A, const unsigned short* __restrict__ Bt,
             const float* __restrict__ bias, float* __restrict__ outf,
             unsigned short* __restrict__ q_ws, unsigned short* __restrict__ kv_ws,
             int M, int N, int K) {
  __shared__ unsigned short As[2][128 * 32];
  __shared__ unsigned short Bs[2][128 * 32];
  const int tid = threadIdx.x;
  const int wid = tid >> 6;
  const int lane = tid & 63;
  const int quad = lane >> 4;
  const int l15 = lane & 15;
  const int m0 = blockIdx.x * 128;
  const int n0 = blockIdx.y * 128;
  const int wm = (wid >> 1) * 64;
  const int wn = (wid & 1) * 64;

  // global_load_lds staging: lane i of wave w -> LDS byte (w*32 rows)*64 + i*16 (LINEAR)
  const int srow = wid * 32 + (lane >> 2);
  const int scol = (lane & 3) * 8;
  // inverse swizzle on the global source: this thread's linear LDS slot is
  // s_phys = ((srow&1)*4 + (lane&3)) in pair P=srow>>1 (P&7 == lane>>3);
  // it must receive logical slot s_log = s_phys ^ (P&7).
  const int sphys = ((lane >> 2) & 1) * 4 + (lane & 3);
  const int slog = sphys ^ (lane >> 3);
  const int r_log = (srow & ~1) | (slog >> 2);
  const int koff = (slog & 3) * 8;
  const unsigned short* ga0 = A + (size_t)(m0 + r_log) * K + koff;
  const unsigned short* ga1 = ga0 + (size_t)16 * K;   // srow+16: P&7 unchanged -> same slog
  const unsigned short* gb0 = Bt + (size_t)(n0 + r_log) * K + koff;
  const unsigned short* gb1 = gb0 + (size_t)16 * K;
  const int la0 = srow * 32 + scol;
  const int la1 = la0 + 16 * 32;

  // fragment-read addressing: row r = w? + i*16 + l15, slot ((r&1)*4+quad)^((r>>1)&7)
  // -> addr = (r>>1)*64 + slot*8 ; (r>>1)&7 == l15>>1 (wm, i*16 are 16-aligned)
  const int sA = (((l15 & 1) * 4 + quad) ^ (l15 >> 1)) * 8;
  const int aBase = wm * 32 + (l15 >> 1) * 64 + sA;  // + i*512
  const int bBase = wn * 32 + (l15 >> 1) * 64 + sA;  // + j*512

#define STAGE(buf, k0)                                                                   \
  do {                                                                                   \
    __builtin_amdgcn_global_load_lds(GLB(ga0 + (k0)), LDS(&As[buf][la0]), 16, 0, 0);     \
    __builtin_amdgcn_global_load_lds(GLB(ga1 + (k0)), LDS(&As[buf][la1]), 16, 0, 0);     \
    __builtin_amdgcn_global_load_lds(GLB(gb0 + (k0)), LDS(&Bs[buf][la0]), 16, 0, 0);     \
    __builtin_amdgcn_global_load_lds(GLB(gb1 + (k0)), LDS(&Bs[buf][la1]), 16, 0, 0);     \
  } while (0)

  f32x4 acc[4][4];
#pragma unroll
  for (int i = 0; i < 4; i++)
#pragma unroll
    for (int j = 0; j < 4; j++) acc[i][j] = (f32x4){0.f, 0.f, 0.f, 0.f};

  STAGE(0, 0);
  __syncthreads();  // drain prologue stage

  int cur = 0;
  for (int k0 = 0; k0 < K; k0 += 32, cur ^= 1) {
    if (k0 + 32 < K) STAGE(cur ^ 1, k0 + 32);  // overlaps with this tile's compute
    short8 af[4], bf[4];
#pragma unroll
    for (int i = 0; i < 4; i++)
      af[i] = *(const short8*)(&As[cur][aBase + i * 512]);
#pragma unroll
    for (int j = 0; j < 4; j++)
      bf[j] = *(const short8*)(&Bs[cur][bBase + j * 512]);
#pragma unroll
    for (int i = 0; i < 4; i++)
#pragma unroll
      for (int j = 0; j < 4; j++)
        acc[i][j] = MFMA32(af[i], bf[j], acc[i][j]);
    __syncthreads();  // drains stage(t+1) + all reads of buf[cur] complete
  }
#undef STAGE

  const int colbase = n0 + wn;  // wave-uniform, 64-aligned; never straddles a 1024-boundary
  const int which = colbase >> 10;

  if (MODE == 0) {
    const int h = (colbase & 1023) >> 6;  // wave-uniform head
    if (which == 2) {
      // ---- V path: acc already d-per-lane / t-consecutive-per-reg; pack ushort4 ----
#pragma unroll
      for (int j = 0; j < 4; j++) {
        const float bv = bias[colbase + j * 16 + l15];
        const int d = j * 16 + l15;
#pragma unroll
        for (int i = 0; i < 4; i++) {
          const int t = m0 + wm + i * 16 + quad * 4;
          const int b = t >> 11;
          const int tt = t & 2047;
          ushort4 pv;
          pv.x = f2bf(acc[i][j][0] + bv);
          pv.y = f2bf(acc[i][j][1] + bv);
          pv.z = f2bf(acc[i][j][2] + bv);
          pv.w = f2bf(acc[i][j][3] + bv);
          const size_t cbase = ((size_t)((b * 16 + h) * 32) + (tt >> 6)) * KV_CHUNK + KV_TILE;
          *(ushort4*)(&kv_ws[cbase + (size_t)d * KV_STRIDE + (tt & 63)]) = pv;
        }
      }
    } else {
      // ---- Q/K path: MFMA-identity transpose -> per-lane 4 consecutive d -> ushort4 ----
      short4v idf;
#pragma unroll
      for (int j4 = 0; j4 < 4; j4++)
        idf[j4] = (quad * 4 + j4 == l15) ? (short)0x3F80 : (short)0;
#pragma unroll
      for (int j = 0; j < 4; j++) {
        const float bv = bias[colbase + j * 16 + l15];
#pragma unroll
        for (int i = 0; i < 4; i++) {
          short4v pf;
          if (which == 0) {
#pragma unroll
            for (int r = 0; r < 4; r++) pf[r] = (short)f2bf((acc[i][j][r] + bv) * QSCALE);
          } else {
#pragma unroll
            for (int r = 0; r < 4; r++) pf[r] = (short)f2bf(acc[i][j][r] + bv);
          }
          f32x4 dt = MFMA16(pf, idf, ((f32x4){0.f, 0.f, 0.f, 0.f}));
          const int t = m0 + wm + i * 16 + l15;  // lane -> t
          const int b = t >> 11;
          const int tt = t & 2047;
          const int dd = j * 16 + quad * 4;  // 4 consecutive d in regs
          ushort4 qv;
          qv.x = f2bf(dt[0]);
          qv.y = f2bf(dt[1]);
          qv.z = f2bf(dt[2]);
          qv.w = f2bf(dt[3]);
          if (which == 0) {
            *(ushort4*)(&q_ws[(((size_t)((b * 16 + h) * 2048) + tt) * 64) + dd]) = qv;
          } else {
            const size_t cbase = ((size_t)((b * 16 + h) * 32) + (tt >> 6)) * KV_CHUNK;
            *(ushort4*)(&kv_ws[cbase + (size_t)(tt & 63) * KV_STRIDE + dd]) = qv;
          }
        }
      }
    }
  } else {
#pragma unroll
    for (int j = 0; j < 4; j++) {
      const int col = colbase + j * 16 + l15;
      const float bv = bias[col];
#pragma unroll
      for (int i = 0; i < 4; i++) {
#pragma unroll
        for (int r = 0; r < 4; r++) {
          const int row = m0 + wm + i * 16 + quad * 4 + r;
          outf[(size_t)row * N + col] = acc[i][j][r] + bv;
        }
      }
    }
  }
}

// ---------------- flash attention (transposed-S, 4-way paired, DMA-pipelined) ----------
// ROUND-3 VERIFIED version, restored permanently. Round 7's F=2 split was
// CORRECT (convicting r5's launch_bounds clamp as the miscompile culprit) but
// SLOWER: 16 ip-blocks double the redundant KV staging (sum chunks/bh 228->392,
// ~+190MB L3->LDS traffic) and the TLP gain didn't compensate. 4-way pairing
// is the staging-redundancy/parallelism balance point.
// q_ws: bf16 [B][H][T][D] (pre-scaled by 0.125*log2e); kv_ws: padded chunk tiles.
// y_ws: bf16 [B][T][C]. Block i (0..7) owns q-tiles {i,15-i,16+i,31-i}*64 (+w*16):
// compute = 66 units for every i (balanced), each staged chunk feeds 4 q-tiles.
// One barrier per 64-key chunk; DMA for c+1 issued right after barrier c.
// Static max: p = exp2(s) directly (softmax scale-invariant in f32; masked -> 0).
// 512 blocks -> 2 blocks/CU; no min-waves clamp (r5 lesson: clamp miscompiles this).

__global__ __launch_bounds__(256)
void attn_fwd(const unsigned short* __restrict__ q_ws, const unsigned short* __restrict__ kv_ws,
              unsigned short* __restrict__ y_ws) {
  __shared__ unsigned short KV[2][KV_CHUNK];  // [K 64x72 | V^T 64x72] per buffer
  const int tid = threadIdx.x;
  const int w = tid >> 6;
  const int lane = tid & 63;
  const int quad = lane >> 4;
  const int l15 = lane & 15;
  const int ip = blockIdx.x;  // 0..7 quad-pair index
  const int bh = blockIdx.y;
  const unsigned short* Qp = q_ws + (size_t)bh * 2048 * 64;
  const unsigned short* KVp = kv_ws + (size_t)bh * 32 * KV_CHUNK;

  int qT[4];
  qT[0] = ip * 64 + w * 16;
  qT[1] = (15 - ip) * 64 + w * 16;
  qT[2] = (16 + ip) * 64 + w * 16;
  qT[3] = (31 - ip) * 64 + w * 16;

  short8 qfr[4][2];
#pragma unroll
  for (int f = 0; f < 4; f++)
#pragma unroll
    for (int c = 0; c < 2; c++)
      qfr[f][c] = *(const short8*)(Qp + (size_t)(qT[f] + l15) * 64 + c * 32 + quad * 8);

  f32x4 o[4][4];
#pragma unroll
  for (int f = 0; f < 4; f++)
#pragma unroll
    for (int db = 0; db < 4; db++) o[f][db] = (f32x4){0.f, 0.f, 0.f, 0.f};
  float lsum[4] = {0.f, 0.f, 0.f, 0.f};  // per-lane partial; reduced in epilogue

  const int nch = 32 - ip;  // 64-key chunks (covers largest tile qT[3])

  // stage chunk 0 into buffer 0 (DMA, no VGPR round trip)
  for (int i = w; i < 18; i += 4)
    __builtin_amdgcn_global_load_lds(GLB(KVp + i * 512 + lane * 8),
                                     LDS(&KV[0][i * 512 + lane * 8]), 16, 0, 0);

  for (int c = 0; c < nch; c++) {
    __syncthreads();  // drains DMA for chunk c (vmcnt0 before barrier)
    const int buf = c & 1;
    if (c + 1 < nch) {  // issue DMA for next chunk; consumed at next barrier
      const unsigned short* src = KVp + (size_t)(c + 1) * KV_CHUNK;
      for (int i = w; i < 18; i += 4)
        __builtin_amdgcn_global_load_lds(GLB(src + i * 512 + lane * 8),
                                         LDS(&KV[buf ^ 1][i * 512 + lane * 8]), 16, 0, 0);
    }
    const unsigned short* Ksb = KV[buf];            // [key][d] stride 72
    const unsigned short* Vtb = KV[buf] + KV_TILE;  // [d][key] stride 72
    const int kbase = c * 64;

#pragma unroll
    for (int tb = 0; tb < 2; tb++) {
      const int kb = kbase + tb * 32;
      if (kb > qT[3] + 15) break;  // wave-uniform
      const int kloc = tb * 32;
      short8 kf[2][2];
#pragma unroll
      for (int t2 = 0; t2 < 2; t2++)
#pragma unroll
        for (int cc = 0; cc < 2; cc++)
          kf[t2][cc] =
              *(const short8*)(&Ksb[(kloc + t2 * 16 + l15) * KV_STRIDE + cc * 32 + quad * 8]);
      short4v vf[2][4];
#pragma unroll
      for (int t2 = 0; t2 < 2; t2++)
#pragma unroll
        for (int db = 0; db < 4; db++)
          vf[t2][db] =
              *(const short4v*)(&Vtb[(db * 16 + l15) * KV_STRIDE + kloc + t2 * 16 + quad * 4]);

#pragma unroll
      for (int f = 0; f < 4; f++) {
        const int qf0 = qT[f];
        if (kb > qf0 + 15) continue;  // wave-uniform skip
        // S^T[key][q]: A=K rows (m=key), B=Q rows (n=q)
        f32x4 s0 = (f32x4){0.f, 0.f, 0.f, 0.f};
        f32x4 s1 = (f32x4){0.f, 0.f, 0.f, 0.f};
        s0 = MFMA32(kf[0][0], qfr[f][0], s0);
        s0 = MFMA32(kf[0][1], qfr[f][1], s0);
        s1 = MFMA32(kf[1][0], qfr[f][0], s1);
        s1 = MFMA32(kf[1][1], qfr[f][1], s1);
        const int qg = qf0 + l15;
        if (kb + 31 > qf0) {  // diagonal-crossing: apply causal mask
#pragma unroll
          for (int r = 0; r < 4; r++) {
            if (kb + quad * 4 + r > qg) s0[r] = -INFINITY;
            if (kb + 16 + quad * 4 + r > qg) s1[r] = -INFINITY;
          }
        }
        float p[8];
#pragma unroll
        for (int r = 0; r < 4; r++) {
          p[r] = __builtin_amdgcn_exp2f(s0[r]);
          p[4 + r] = __builtin_amdgcn_exp2f(s1[r]);
        }
        lsum[f] += ((p[0] + p[1]) + (p[2] + p[3])) + ((p[4] + p[5]) + (p[6] + p[7]));
        // pack P to bf16 B-frags for 16x16x16 (k=quad*4+j matches C-layout rows)
        u32 u[8];
#pragma unroll
        for (int i = 0; i < 8; i++) u[i] = __float_as_uint(p[i]) + 0x8000u;
        uint2v t0, t1;
        t0.x = __builtin_amdgcn_perm(u[1], u[0], 0x07060302u);
        t0.y = __builtin_amdgcn_perm(u[3], u[2], 0x07060302u);
        t1.x = __builtin_amdgcn_perm(u[5], u[4], 0x07060302u);
        t1.y = __builtin_amdgcn_perm(u[7], u[6], 0x07060302u);
        short4v pf0 = __builtin_bit_cast(short4v, t0);
        short4v pf1 = __builtin_bit_cast(short4v, t1);
#pragma unroll
        for (int db = 0; db < 4; db++) {
          o[f][db] = MFMA16(vf[0][db], pf0, o[f][db]);
          o[f][db] = MFMA16(vf[1][db], pf1, o[f][db]);
        }
      }
    }
  }

  const int b = bh >> 4, h = bh & 15;
#pragma unroll
  for (int f = 0; f < 4; f++) {
    float ls = lsum[f];
    ls += __shfl_xor(ls, 16);
    ls += __shfl_xor(ls, 32);
    const int qg = qT[f] + l15;
    const float inv = 1.0f / ls;
    const size_t rowoff = ((size_t)(b * 2048 + qg)) * 1024 + h * 64;
#pragma unroll
    for (int db = 0; db < 4; db++) {
      ushort4 ov;
      ov.x = f2bf(o[f][db][0] * inv);
      ov.y = f2bf(o[f][db][1] * inv);
      ov.z = f2bf(o[f][db][2] * inv);
      ov.w = f2bf(o[f][db][3] * inv);
      *(ushort4*)(y_ws + rowoff + db * 16 + quad * 4) = ov;
    }
  }
}

// ---------------- launch ----------------

extern "C" void kernel_launch(void* const* d_in, const int* in_sizes, int n_in,
                              void* d_out, int out_size, void* d_ws, size_t ws_size,
                              hipStream_t stream) {
  const float* x = (const float*)d_in[0];
  const float* w_attn = (const float*)d_in[1];
  const float* b_attn = (const float*)d_in[2];
  const float* w_proj = (const float*)d_in[3];
  const float* b_proj = (const float*)d_in[4];
  float* out = (float*)d_out;

  // Workspace: ~80 MB total (96.5 MB in an earlier round overflowed ws_size).
  unsigned short* xb = (unsigned short*)d_ws;          // 8192*1024 (bf16 x)
  unsigned short* wat = xb + (size_t)8192 * 1024;      // 3072*1024 (w_attn^T)
  unsigned short* wpt = wat + (size_t)3072 * 1024;     // 1024*1024 (w_proj^T)
  unsigned short* q_ws = wpt + (size_t)1024 * 1024;    // [B][H][T][D]
  unsigned short* kv_ws = q_ws + (size_t)8388608;      // [bh][chunk] padded K|V^T tiles
  // y_ws ALIASES xb: xb is only read by gemm0, which completes before attn writes y.
  unsigned short* y_ws = xb;                           // [B][T][C]

  prep_fused<<<6144, 256, 0, stream>>>(x, xb, w_attn, wat, w_proj, wpt);

  gemm_bt<0><<<dim3(64, 24), 256, 0, stream>>>(xb, wat, b_attn, nullptr, q_ws, kv_ws,
                                               8192, 3072, 1024);
  attn_fwd<<<dim3(8, 64), 256, 0, stream>>>(q_ws, kv_ws, y_ws);
  gemm_bt<1><<<dim3(64, 8), 256, 0, stream>>>(y_ws, wpt, b_proj, out, nullptr, nullptr,
                                              8192, 1024, 1024);
}